// Round 10
// baseline (40.161 us; speedup 1.0000x reference)
//
#include <hip/hip_runtime.h>
#include <math.h>

// RefractiveInterface: Ferrari quartic solve. fp64 kept ONLY for the
// cancellation-heavy resolvent chain, one Halley polish of true resolvent
// roots, and the D1/D2 discriminants (classification-critical). All branch
// bodies run in fp32. Every discrete decision boundary (Dc sign, aa/bb
// signs, junk real<0 gates, cost/err argmins, imag-classification) carries
// a guard window; lanes inside any window rerun the full fp64 reference
// path (round-9 kernel) via a noinline rescue (~1e-4 of lanes).

__device__ __forceinline__ float fast_rcp(float x) { return __builtin_amdgcn_rcpf(x); }
__device__ __forceinline__ float fast_rsq(float x) { return __builtin_amdgcn_rsqf(x); }

// fp32 cube root of x>=0 (~1 ulp): exp2/log2 seed + 1 NR (division-free)
__device__ __forceinline__ float cbrtf_pos(float x) {
    float w = __builtin_amdgcn_exp2f(__builtin_amdgcn_logf(x) * (-1.0f / 3.0f));
    w = w * (4.0f - x * ((w * w) * w)) * (1.0f / 3.0f);
    float c = x * (w * w);
    return (x < 1e-30f) ? 0.0f : c;
}

// fp64 cube root pair (c = x^(1/3), w = x^(-1/3)), ~1e-14 rel (rescue path)
__device__ __forceinline__ void cbrt_cw64(double x, double& c, double& w) {
    float xf = (float)x;
    float wf = __builtin_amdgcn_exp2f(__builtin_amdgcn_logf(xf) * (-1.0f / 3.0f));
    double wd = (double)wf;
    wd = wd * (4.0 - x * ((wd * wd) * wd)) * (1.0 / 3.0);
    bool tiny = (x < 1e-30);
    w = tiny ? 0.0 : wd;
    c = tiny ? 0.0 : x * (wd * wd);
}

// Full-precision reference path (round-9 logic, post-chain). Called for
// flagged lanes only.
__device__ __attribute__((noinline)) float rescue_fp64(
    double q, double q2, double B1n, double mql, double pc3,
    double Dc, double sh, double p2d,
    float u, float mm2, float mude2, float vd)
{
    double t;
    if (Dc < 0.0) {
        float R2f = (float)(-pc3);
        float Rf  = sqrtf(R2f);
        float cphi = (float)mql * fast_rcp(R2f * Rf);
        cphi = fminf(fmaxf(cphi, -1.0f), 1.0f);
        float T = 0.5f + sqrtf((1.0f + cphi) * (1.0f / 6.0f));
        #pragma unroll
        for (int k = 0; k < 3; ++k) {
            float g  = fmaf(fmaf(4.0f * T, T, -3.0f), T, -cphi);
            float gp = fmaf(12.0f * T, T, -3.0f);
            T -= g * fast_rcp(gp + 1e-12f);
        }
        t = (double)(2.0f * Rf * T) - sh;
        double f   = ((t + p2d) * t + B1n) * t - q2;
        double fp_ = fma(3.0 * t + p2d, t, (t * p2d + B1n));
        double fpp = 6.0 * t + 2.0 * p2d;
        double den = fp_ * fp_ - 0.5 * f * fpp;
        double inv = (double)fast_rcp((float)den);
        inv = inv * (2.0 - den * inv);
        double dt  = (f * fp_) * inv;
        if (isfinite(dt) && fabs(dt) < 0.1 * fabs(t) + 1e-2) t -= dt;
    } else {
        double rcr;
        if (Dc < 1e-36) rcr = 0.0;
        else {
            double z = (double)fast_rsq((float)Dc);
            z = z * (1.5 - 0.5 * Dc * (z * z));
            rcr = Dc * z;
        }
        double aa = mql + rcr, bb = mql - rcr;
        bool na = (aa < 0.0), nb = (bb < 0.0);
        double absa = fabs(aa), absb = fabs(bb);
        bool aBig = (absa >= absb);
        double big = aBig ? absa : absb;
        double cbig, wbig;
        cbrt_cw64(big, cbig, wbig);
        double csml = fabs(pc3) * wbig;
        double ca = aBig ? cbig : csml;
        double cb = aBig ? csml : cbig;
        if (!na && !nb) {
            double s = ca + cb;
            double u0r = s - sh;
            t = (u0r >= 0.0) ? u0r : fma(-0.5, s, -sh);
        } else {
            const double CI = 0.8660254037844386;
            double Lre = na ? 0.5 * ca : ca;
            double Lim = na ? CI * ca  : 0.0;
            double Rre = nb ? 0.5 * cb : cb;
            double Rim = nb ? CI * cb  : 0.0;
            double u0r = (Lre + Rre) - sh;
            double u0i =  Lim + Rim;
            double u1r = (-0.5 * Lre + CI * Lim) + (-0.5 * Rre - CI * Rim) - sh;
            double u1i = (-0.5 * Lim - CI * Lre) + (-0.5 * Rim + CI * Rre);
            double u2r = (-0.5 * Lre - CI * Lim) + (-0.5 * Rre + CI * Rim) - sh;
            double u2i = (-0.5 * Lim + CI * Lre) + (-0.5 * Rim - CI * Rre);
            double c0 = (u0r < 0.0) ? 1e6 : fabs(u0i);
            double c1 = (u1r < 0.0) ? 1e6 : fabs(u1i);
            double c2 = (u2r < 0.0) ? 1e6 : fabs(u2i);
            double cbest = c0; t = u0r;
            if (c1 < cbest) { cbest = c1; t = u1r; }
            if (c2 < cbest) { t = u2r; }
        }
    }

    t = fmax(t, 1e-6);
    double rs = (double)fast_rsq((float)t);
    rs = rs * (1.5 - 0.5 * t * (rs * rs));
    double wq = 2.0 * (q * rs);
    double tp = t + p2d;
    double D1 = wq - tp;
    double D2 = -wq - tp;

    float s1r = 0.0f, s1i = 0.0f, s2r = 0.0f, s2i = 0.0f;
    if (D1 >= 0.0) s1r = sqrtf((float)D1); else s1i = sqrtf((float)(-D1));
    if (D2 >= 0.0) s2r = sqrtf((float)D2); else s2i = sqrtf((float)(-D2));
    bool im1 = (s1i * 0.5f > 0.001f);
    bool im2 = (s2i * 0.5f > 0.001f);

    float stf = (float)(t * rs);
    float uh  = 0.5f * u;
    float xr0 = (-stf + s1r) * 0.5f + uh;
    float xr1 = (-stf - s1r) * 0.5f + uh;
    float xr2 = ( stf + s2r) * 0.5f + uh;
    float xr3 = ( stf - s2r) * 0.5f + uh;

    float g0 = fmaf(mm2, xr0 * xr0, mude2);
    float g1 = fmaf(mm2, xr1 * xr1, mude2);
    float g2 = fmaf(mm2, xr2 * xr2, mude2);
    float g3 = fmaf(mm2, xr3 * xr3, mude2);
    float e0 = im1 ? INFINITY : fabsf((u - xr0) * sqrtf(g0) - vd * xr0);
    float e1 = im1 ? INFINITY : fabsf((u - xr1) * sqrtf(g1) - vd * xr1);
    float e2 = im2 ? INFINITY : fabsf((u - xr2) * sqrtf(g2) - vd * xr2);
    float e3 = im2 ? INFINITY : fabsf((u - xr3) * sqrtf(g3) - vd * xr3);

    float best = xr0; float eb = e0;
    if (e1 < eb) { eb = e1; best = xr1; }
    if (e2 < eb) { eb = e2; best = xr2; }
    if (e3 < eb) { eb = e3; best = xr3; }
    return best;
}

__global__ __launch_bounds__(256) void refract_kernel(
    const float* __restrict__ pos,
    const float* __restrict__ nrm,
    const float* __restrict__ dpt,
    float* __restrict__ out,
    int N)
{
    int i = blockIdx.x * blockDim.x + threadIdx.x;
    if (i >= N) return;

    const float mu = 1.33f;
    float n0 = nrm[0], n1 = nrm[1];
    float d_eff = fmaxf(dpt[0], 0.0f) + 0.001f;

    // ---- fp32 geometry ----
    float nn = sqrtf(n0 * n0 + n1 * n1 + 1.0f);
    float z1x = n0 / nn, z1y = n1 / nn, z1z = 1.0f / nn;

    float px = pos[3 * i + 0], py = pos[3 * i + 1], pz = pos[3 * i + 2];

    float cux = z1y * pz - z1z * py;
    float cuy = z1z * px - z1x * pz;
    float cuz = z1x * py - z1y * px;
    float pn = sqrtf(cux * cux + cuy * cuy + cuz * cuz);
    float u = -pn;
    float ipn = fast_rcp(pn);
    float z2x = (z1y * cuz - z1z * cuy) * ipn;
    float z2y = (z1z * cux - z1x * cuz) * ipn;
    float z2z = (z1x * cuy - z1y * cux) * ipn;

    float v = px * z1x + py * z1y + pz * z1z;

    float c3f = d_eff * d_eff * mu * mu - d_eff * d_eff + 2.0f * d_eff * v
              + mu * mu * u * u - u * u - v * v;

    // ---- fp64 resolvent chain (cancellation-sensitive; kept fp64) ----
    const double invc1 = 1.0 / (double)((1.33f - 1.0f) * (1.33f + 1.0f));
    const double mu2d = (double)(1.33f) * (double)(1.33f);
    double dm = (double)d_eff;
    double km = -2.0 * dm * dm * mu2d * invc1;

    double ud = (double)u;
    double G  = (double)c3f * invc1;
    double U  = ud * ud;
    double p  = fma(-1.5, U, G);
    double q  = ud * ((G - U) + km);
    double r  = 0.25 * U * fma(-0.75, U, G);
    double p2 = p * p;
    double q2 = q * q;
    double pr = p * r;
    double p3 = p2 * p;
    double mql = fma(p3, 1.0 / 27.0, fma(pr, -4.0 / 3.0, 0.5 * q2));
    double pc3 = fma(p2, -1.0 / 9.0, (-4.0 / 3.0) * r);
    double pc33 = (pc3 * pc3) * pc3;
    double mql2 = mql * mql;
    double Dc   = pc33 + (mql2 + 1e-12);
    double scDc = fabs(pc33) + mql2 + 1e-12;
    double sh  = p * (2.0 / 3.0);
    double p2d = p + p;
    double B1n = fma(-4.0, r, p2);

    bool flag = fabs(Dc) < 1e-12 * scDc;          // Dc-sign guard

    float mqlf = (float)mql;
    float shf  = (float)sh;

    double t;
    bool polish = false;

    if (Dc < 0.0) {
        // 3 real resolvent roots: largest via fp32 trig-Newton seed
        float R2f = (float)(-pc3);
        float Rf  = sqrtf(R2f);
        float cphi = mqlf * fast_rcp(R2f * Rf);
        cphi = fminf(fmaxf(cphi, -1.0f), 1.0f);
        float T = 0.5f + sqrtf((1.0f + cphi) * (1.0f / 6.0f));
        #pragma unroll
        for (int k = 0; k < 3; ++k) {
            float g  = fmaf(fmaf(4.0f * T, T, -3.0f), T, -cphi);
            float gp = fmaf(12.0f * T, T, -3.0f);
            T -= g * fast_rcp(gp + 1e-12f);
        }
        t = (double)(2.0f * Rf * T) - sh;
        polish = true;
    } else {
        float rcrf = sqrtf((float)Dc);
        float aaf = mqlf + rcrf;
        float bbf = mqlf - rcrf;
        float abscale = fabsf(mqlf) + rcrf + 1e-20f;
        flag = flag || (fabsf(aaf) < 2e-5f * abscale)    // cbrt slope is
                    || (fabsf(bbf) < 2e-5f * abscale);   // infinite at 0
        bool na = (aaf < 0.0f), nb = (bbf < 0.0f);
        float caf = cbrtf_pos(fabsf(aaf));
        float cbf = cbrtf_pos(fabsf(bbf));

        if (!na && !nb) {
            float s = caf + cbf;
            float u0rf = s - shf;
            flag = flag || (fabsf(u0rf) < 3e-6f * (s + fabsf(shf) + 1e-20f));
            if (u0rf >= 0.0f) { t = (double)u0rf; polish = true; }
            else              { t = (double)fmaf(-0.5f, s, -shf); }
        } else {
            // fp32 principal-branch Cardano junk replication
            const float CI = 0.8660254f;
            float Lre = na ? 0.5f * caf : caf;
            float Lim = na ? CI * caf   : 0.0f;
            float Rre = nb ? 0.5f * cbf : cbf;
            float Rim = nb ? CI * cbf   : 0.0f;
            float u0r = (Lre + Rre) - shf;
            float u0i =  Lim + Rim;
            float u1r = (-0.5f * Lre + CI * Lim) + (-0.5f * Rre - CI * Rim) - shf;
            float u1i = (-0.5f * Lim - CI * Lre) + (-0.5f * Rim + CI * Rre);
            float u2r = (-0.5f * Lre - CI * Lim) + (-0.5f * Rre + CI * Rim) - shf;
            float u2i = (-0.5f * Lim + CI * Lre) + (-0.5f * Rim - CI * Rre);

            float jscale = caf + cbf + fabsf(shf) + 1e-20f;
            flag = flag || (fabsf(u0r) < 1e-5f * jscale)   // real<0 gates
                        || (fabsf(u1r) < 1e-5f * jscale)
                        || (fabsf(u2r) < 1e-5f * jscale);

            float c0 = (u0r < 0.0f) ? 1e6f : fabsf(u0i);
            float c1 = (u1r < 0.0f) ? 1e6f : fabsf(u1i);
            float c2 = (u2r < 0.0f) ? 1e6f : fabsf(u2i);
            float cbest = c0, tsel = u0r, csec;
            if (c1 < cbest) { csec = cbest; cbest = c1; tsel = u1r; }
            else            { csec = c1; }
            if (c2 < cbest) { csec = cbest; cbest = c2; tsel = u2r; }
            else            { csec = fminf(csec, c2); }
            flag = flag || ((csec - cbest) < 1e-4f * (cbest + 1e-3f));
            t = (double)tsel;
        }
    }

    if (polish) {
        // one fp64 Halley anchoring t to the exact resolvent coefficients
        double f   = ((t + p2d) * t + B1n) * t - q2;
        double fp_ = fma(3.0 * t + p2d, t, (t * p2d + B1n));
        double fpp = 6.0 * t + 2.0 * p2d;
        double den = fp_ * fp_ - 0.5 * f * fpp;
        double inv = (double)fast_rcp((float)den);
        inv = inv * (2.0 - den * inv);
        double dt  = (f * fp_) * inv;
        if (isfinite(dt) && fabs(dt) < 0.1 * fabs(t) + 1e-2) t -= dt;
        else flag = true;
    }

    t = fmax(t, 1e-6);
    // fp64 D-tail (classification-critical)
    double rs = (double)fast_rsq((float)t);
    rs = rs * (1.5 - 0.5 * t * (rs * rs));
    double wq = 2.0 * (q * rs);
    double tp = t + p2d;
    double D1 = wq - tp;
    double D2 = -wq - tp;

    float D1f = (float)D1, D2f = (float)D2;
    float MDf = fabsf((float)wq) + fabsf((float)tp);
    float wwin = (polish ? 1e-7f : 1e-4f * (1.0f + MDf)) + 5e-6f;
    flag = flag || (fabsf(D1f) < wwin) || (fabsf(D2f) < wwin);

    float s1r = 0.0f, s1i = 0.0f, s2r = 0.0f, s2i = 0.0f;
    if (D1 >= 0.0) s1r = sqrtf(D1f); else s1i = sqrtf(-D1f);
    if (D2 >= 0.0) s2r = sqrtf(D2f); else s2i = sqrtf(-D2f);
    bool im1 = (s1i * 0.5f > 0.001f);
    bool im2 = (s2i * 0.5f > 0.001f);

    float stf = (float)(t * rs);
    float uh  = 0.5f * u;
    float xr0 = (-stf + s1r) * 0.5f + uh;
    float xr1 = (-stf - s1r) * 0.5f + uh;
    float xr2 = ( stf + s2r) * 0.5f + uh;
    float xr3 = ( stf - s2r) * 0.5f + uh;

    float mm2 = mu * mu - 1.0f;
    float mude2 = mu * mu * d_eff * d_eff;
    float vd = v - d_eff;
    float g0 = fmaf(mm2, xr0 * xr0, mude2);
    float g1 = fmaf(mm2, xr1 * xr1, mude2);
    float g2 = fmaf(mm2, xr2 * xr2, mude2);
    float g3 = fmaf(mm2, xr3 * xr3, mude2);
    float e0 = im1 ? INFINITY : fabsf((u - xr0) * sqrtf(g0) - vd * xr0);
    float e1 = im1 ? INFINITY : fabsf((u - xr1) * sqrtf(g1) - vd * xr1);
    float e2 = im2 ? INFINITY : fabsf((u - xr2) * sqrtf(g2) - vd * xr2);
    float e3 = im2 ? INFINITY : fabsf((u - xr3) * sqrtf(g3) - vd * xr3);

    // argmin with runner-up tracking (first-occurrence on ties)
    float eb = e0, xb = xr0, eb2, xb2;
    if (e1 < eb) { eb2 = eb; xb2 = xb; eb = e1; xb = xr1; }
    else         { eb2 = e1; xb2 = xr1; }
    if (e2 < eb) { eb2 = eb; xb2 = xb; eb = e2; xb = xr2; }
    else if (e2 < eb2) { eb2 = e2; xb2 = xr2; }
    if (e3 < eb) { eb2 = eb; xb2 = xb; eb = e3; xb = xr3; }
    else if (e3 < eb2) { eb2 = e3; xb2 = xr3; }

    // argmin-flip guard: near-tie between geometrically distant roots
    float margin = (polish ? 3e-5f : 3e-4f) * (1.0f + eb) + 1e-6f;
    if (((eb2 - eb) < margin) && (fabsf(xb2 - xb) > 3e-2f)) flag = true;

    float best = xb;
    if (__builtin_expect(flag, 0)) {
        best = rescue_fp64(q, q2, B1n, mql, pc3, Dc, sh, p2d,
                           u, mm2, mude2, vd);
    }

    out[3 * i + 0] = best * z2x + d_eff * z1x;
    out[3 * i + 1] = best * z2y + d_eff * z1y;
    out[3 * i + 2] = best * z2z + d_eff * z1z;
}

extern "C" void kernel_launch(void* const* d_in, const int* in_sizes, int n_in,
                              void* d_out, int out_size, void* d_ws, size_t ws_size,
                              hipStream_t stream) {
    const float* pos = (const float*)d_in[0];
    const float* nrm = (const float*)d_in[1];
    const float* dpt = (const float*)d_in[2];
    float* out = (float*)d_out;
    int N = in_sizes[0] / 3;
    int block = 256;
    int grid = (N + block - 1) / block;
    refract_kernel<<<grid, block, 0, stream>>>(pos, nrm, dpt, out, N);
}

// Round 11
// 28.659 us; speedup vs baseline: 1.4014x; 1.4014x over previous
//
#include <hip/hip_runtime.h>
#include <math.h>

// RefractiveInterface: per-ray Ferrari quartic solve (round-9 structure).
// Round-11 changes: (1) 2 rays per thread (independent chains interleave to
// fill the ~20% issue-idle from serial fp64 NR/Halley dependency chains);
// (2) junk-path omega combos collapsed to a rotation-coefficient table
// (L=ca*cis(na*pi/3), R=cb*cis(nb*pi/3); coefs in {0,+-0.5,+-1}x{0,+-CI}).

__device__ __forceinline__ float fast_rcp(float x) { return __builtin_amdgcn_rcpf(x); }
__device__ __forceinline__ float fast_rsq(float x) { return __builtin_amdgcn_rsqf(x); }

// cube root of x>=0: returns c = x^(1/3), w = x^(-1/3) (~1e-14 rel).
__device__ __forceinline__ void cbrt_cw(double x, double& c, double& w) {
    float xf = (float)x;
    float wf = __builtin_amdgcn_exp2f(__builtin_amdgcn_logf(xf) * (-1.0f / 3.0f));
    double wd = (double)wf;
    wd = wd * (4.0 - x * ((wd * wd) * wd)) * (1.0 / 3.0);
    bool tiny = (x < 1e-30);
    w = tiny ? 0.0 : wd;
    c = tiny ? 0.0 : x * (wd * wd);
}

__device__ __forceinline__ float solve_ray(
    float px, float py, float pz,
    float z1x, float z1y, float z1z, float d_eff,
    float& z2x, float& z2y, float& z2z)
{
    const float mu = 1.33f;

    // cu = cross(z1, pos);  u = -||cu||;  z2 = cross(z1, cu)/||cu||
    float cux = z1y * pz - z1z * py;
    float cuy = z1z * px - z1x * pz;
    float cuz = z1x * py - z1y * px;
    float pn = sqrtf(cux * cux + cuy * cuy + cuz * cuz);
    float u = -pn;
    float ipn = fast_rcp(pn);
    z2x = (z1y * cuz - z1z * cuy) * ipn;
    z2y = (z1z * cux - z1x * cuz) * ipn;
    z2z = (z1x * cuy - z1y * cux) * ipn;

    float v = px * z1x + py * z1y + pz * z1z;

    float c3f = d_eff * d_eff * mu * mu - d_eff * d_eff + 2.0f * d_eff * v
              + mu * mu * u * u - u * u - v * v;

    // ---- fp64 collapsed coefficient chain ----
    const double invc1 = 1.0 / (double)((1.33f - 1.0f) * (1.33f + 1.0f));
    const double mu2d = (double)(1.33f) * (double)(1.33f);
    double dm = (double)d_eff;
    double km = -2.0 * dm * dm * mu2d * invc1;

    double ud = (double)u;
    double G  = (double)c3f * invc1;
    double U  = ud * ud;
    double p  = fma(-1.5, U, G);
    double q  = ud * ((G - U) + km);
    double r  = 0.25 * U * fma(-0.75, U, G);
    double p2 = p * p;
    double q2 = q * q;
    double pr = p * r;
    double p3 = p2 * p;
    double mql = fma(p3, 1.0 / 27.0, fma(pr, -4.0 / 3.0, 0.5 * q2));
    double pc3 = fma(p2, -1.0 / 9.0, (-4.0 / 3.0) * r);
    double Dc  = fma(pc3 * pc3, pc3, fma(mql, mql, 1e-12));
    double sh  = p * (2.0 / 3.0);
    double p2d = p + p;

    double t;

    if (Dc < 0.0) {
        // 3 genuine real roots; largest. 4T^3-3T = cphi, T = cos(acos/3)
        float R2f = (float)(-pc3);
        float Rf  = sqrtf(R2f);
        float cphi = (float)mql * fast_rcp(R2f * Rf);
        cphi = fminf(fmaxf(cphi, -1.0f), 1.0f);
        float T = 0.5f + sqrtf((1.0f + cphi) * (1.0f / 6.0f));
        #pragma unroll
        for (int k = 0; k < 3; ++k) {
            float g  = fmaf(fmaf(4.0f * T, T, -3.0f), T, -cphi);
            float gp = fmaf(12.0f * T, T, -3.0f);
            T -= g * fast_rcp(gp + 1e-12f);
        }
        t = (double)(2.0f * Rf * T) - sh;

        // Halley on f(t) = ((t+2p)t + (p^2-4r))t - q^2
        double B1n = fma(-4.0, r, p2);
        double f   = ((t + p2d) * t + B1n) * t - q2;
        double fp  = fma(3.0 * t + p2d, t, (t * p2d + B1n));
        double fpp = 6.0 * t + 2.0 * p2d;
        double den = fp * fp - 0.5 * f * fpp;
        double inv = (double)fast_rcp((float)den);
        inv = inv * (2.0 - den * inv);
        double dt  = (f * fp) * inv;
        if (isfinite(dt) && fabs(dt) < 0.1 * fabs(t) + 1e-2) t -= dt;
    } else {
        // rcr = sqrt(Dc): fp32 rsq seed + one fp64 NR
        double rcr;
        if (Dc < 1e-36) {
            rcr = 0.0;
        } else {
            double z = (double)fast_rsq((float)Dc);
            z = z * (1.5 - 0.5 * Dc * (z * z));
            rcr = Dc * z;
        }
        double aa = mql + rcr;
        double bb = mql - rcr;
        bool na = (aa < 0.0), nb = (bb < 0.0);

        // single cbrt: |aa|*|bb| = |pc3|^3 -> cbrt the larger, derive smaller
        double absa = fabs(aa), absb = fabs(bb);
        bool aBig = (absa >= absb);
        double big = aBig ? absa : absb;
        double cbig, wbig;
        cbrt_cw(big, cbig, wbig);
        double csml = fabs(pc3) * wbig;
        double ca = aBig ? cbig : csml;
        double cb = aBig ? csml : cbig;

        if (!na && !nb) {
            // genuine: u0 = ca+cb-sh (imag 0) when >=0; else conj-pair first
            double s = ca + cb;
            double u0r = s - sh;
            t = (u0r >= 0.0) ? u0r : fma(-0.5, s, -sh);
        } else {
            // junk: rotation-coefficient table (verified vs omega combos)
            const double CI = 0.8660254037844386;   // sqrt(3)/2
            double u0r = (na ? 0.5 * ca : ca) + (nb ? 0.5 * cb : cb) - sh;
            double u0i = CI * ((na ? ca : 0.0) + (nb ? cb : 0.0));
            double u1r = (na ? 0.5 * ca : -0.5 * ca) + (nb ? -cb : -0.5 * cb) - sh;
            double u1i = CI * ((nb ? 0.0 : cb) - ca);
            double u2r = (na ? -ca : -0.5 * ca) + (nb ? 0.5 * cb : -0.5 * cb) - sh;
            double u2i = CI * ((na ? 0.0 : ca) - cb);

            double c0 = (u0r < 0.0) ? 1e6 : fabs(u0i);
            double c1 = (u1r < 0.0) ? 1e6 : fabs(u1i);
            double c2 = (u2r < 0.0) ? 1e6 : fabs(u2i);
            double cbest = c0; t = u0r;
            if (c1 < cbest) { cbest = c1; t = u1r; }
            if (c2 < cbest) { t = u2r; }
        }
    }

    t = fmax(t, 1e-6);
    // rs = 1/sqrt(t): fp32 HW seed + one fp64 NR
    double rs = (double)fast_rsq((float)t);
    rs = rs * (1.5 - 0.5 * t * (rs * rs));
    double st = t * rs;
    // D1 = 2*q*rs - (t+2p), D2 = -2*q*rs - (t+2p)
    double tp = t + p2d;
    double wq = 2.0 * (q * rs);
    double D1 = wq - tp;
    double D2 = -wq - tp;

    float s1r = 0.0f, s1i = 0.0f, s2r = 0.0f, s2i = 0.0f;
    if (D1 >= 0.0) s1r = sqrtf((float)D1); else s1i = sqrtf((float)(-D1));
    if (D2 >= 0.0) s2r = sqrtf((float)D2); else s2i = sqrtf((float)(-D2));
    bool im1 = (s1i * 0.5f > 0.001f);
    bool im2 = (s2i * 0.5f > 0.001f);

    float stf = (float)st;
    float uh  = 0.5f * u;                 // -h (h = -u/2)
    float xr0 = (-stf + s1r) * 0.5f + uh;
    float xr1 = (-stf - s1r) * 0.5f + uh;
    float xr2 = ( stf + s2r) * 0.5f + uh;
    float xr3 = ( stf - s2r) * 0.5f + uh;

    // fp32 error metric: e = |(u-x)*sqrt(mu^2 d^2 + (mu^2-1) x^2) - (v-d)x|
    float mm2 = mu * mu - 1.0f;
    float mude2 = mu * mu * d_eff * d_eff;
    float vd = v - d_eff;
    float g0 = fmaf(mm2, xr0 * xr0, mude2);
    float g1 = fmaf(mm2, xr1 * xr1, mude2);
    float g2 = fmaf(mm2, xr2 * xr2, mude2);
    float g3 = fmaf(mm2, xr3 * xr3, mude2);
    float e0 = im1 ? INFINITY : fabsf((u - xr0) * sqrtf(g0) - vd * xr0);
    float e1 = im1 ? INFINITY : fabsf((u - xr1) * sqrtf(g1) - vd * xr1);
    float e2 = im2 ? INFINITY : fabsf((u - xr2) * sqrtf(g2) - vd * xr2);
    float e3 = im2 ? INFINITY : fabsf((u - xr3) * sqrtf(g3) - vd * xr3);

    float best = xr0; float eb = e0;
    if (e1 < eb) { eb = e1; best = xr1; }
    if (e2 < eb) { eb = e2; best = xr2; }
    if (e3 < eb) { eb = e3; best = xr3; }
    return best;
}

__global__ __launch_bounds__(256) void refract_kernel(
    const float* __restrict__ pos,
    const float* __restrict__ nrm,
    const float* __restrict__ dpt,
    float* __restrict__ out,
    int N)
{
    int T = (N + 1) >> 1;
    int tid = blockIdx.x * blockDim.x + threadIdx.x;
    if (tid >= T) return;

    float n0 = nrm[0], n1 = nrm[1];
    float d_eff = fmaxf(dpt[0], 0.0f) + 0.001f;
    float nn = sqrtf(n0 * n0 + n1 * n1 + 1.0f);
    float z1x = n0 / nn, z1y = n1 / nn, z1z = 1.0f / nn;

    // ray 0: coalesced block [0, T)
    {
        int i = tid;
        float z2x, z2y, z2z;
        float best = solve_ray(pos[3 * i + 0], pos[3 * i + 1], pos[3 * i + 2],
                               z1x, z1y, z1z, d_eff, z2x, z2y, z2z);
        out[3 * i + 0] = best * z2x + d_eff * z1x;
        out[3 * i + 1] = best * z2y + d_eff * z1y;
        out[3 * i + 2] = best * z2z + d_eff * z1z;
    }
    // ray 1: coalesced block [T, N)
    int i1 = tid + T;
    if (i1 < N) {
        float z2x, z2y, z2z;
        float best = solve_ray(pos[3 * i1 + 0], pos[3 * i1 + 1], pos[3 * i1 + 2],
                               z1x, z1y, z1z, d_eff, z2x, z2y, z2z);
        out[3 * i1 + 0] = best * z2x + d_eff * z1x;
        out[3 * i1 + 1] = best * z2y + d_eff * z1y;
        out[3 * i1 + 2] = best * z2z + d_eff * z1z;
    }
}

extern "C" void kernel_launch(void* const* d_in, const int* in_sizes, int n_in,
                              void* d_out, int out_size, void* d_ws, size_t ws_size,
                              hipStream_t stream) {
    const float* pos = (const float*)d_in[0];
    const float* nrm = (const float*)d_in[1];
    const float* dpt = (const float*)d_in[2];
    float* out = (float*)d_out;
    int N = in_sizes[0] / 3;
    int T = (N + 1) >> 1;
    int block = 256;
    int grid = (T + block - 1) / block;
    refract_kernel<<<grid, block, 0, stream>>>(pos, nrm, dpt, out, N);
}